// Round 8
// baseline (408.806 us; speedup 1.0000x reference)
//
#include <hip/hip_runtime.h>
#include <cstddef>
#include <cstdint>

// ST-GCN block. Round-8: 4 blocks/CU via smaller LDS + per-s pipelined handoff.
//  R7 post-mortem: pinned prefetch changed nothing (VGPR stayed 84, dur -2%) ->
//  load latency was NOT the stall. All pipes <27%, occupancy 26% -> TLP shortage:
//  ~2 waves/SIMD cannot fill the long serial chain (dsread->MFMA->pack->dswrite->
//  FULL lgkm fence->dsread->MFMA->vmcnt->convert).
//  Changes:
//   - Handoff scratch shrunk 24.6KB -> 2x8KB rotating buffers; stage-1(s) writes
//     4 tiles, short fence, stage-2(s) reads them, rotating s&1. Serial chain is
//     3 short write->fence->read hops (interleavable with MFMA) instead of one
//     monolithic 12-write fence.
//   - LDS 43.5 -> 35.3KB; __launch_bounds__(256,4): 4 blocks/CU = 16 waves/CU
//     (VGPR-84 ceiling). The R2 (256,4) disaster needed sinkable reg-prefetch;
//     prefetch is asm-pinned now (R7-proven).
//  Kept from R6/R7 (all verified): single barrier/iter (lgkm-only drain, stores
//  fly across iterations), o-block wave mapping, wave-private handoff indexing,
//  dense float2 epilogue, pinned-issue prefetch + data-carrying vmcnt fence.
// Sync proof: [B0_t, B0_{t+1}): Xb[cur] read-only, Xb[cur^1] written only by
//   convert (ordered by B0's lgkmcnt(0)+barrier). sbuf[*] wave-private
//   (same-wave DS ordering + per-s lgkmcnt(0) fences).
#define N_  32
#define C_  64
#define T_  300
#define V_  25
#define M_  2
#define S_  3
#define O_  64
#define OS_ 192
#define TB  6             // t-values per block
#define NT_BLK (T_/TB)    // 50
#define CTVM (C_*T_*V_*M_)   // 960000
#define TVM  (T_*V_*M_)      // 15000
#define VM   (V_*M_)         // 50
#define XPITCH 72         // shorts; 144B rows

typedef short  short8  __attribute__((ext_vector_type(8)));
typedef float  float4_ __attribute__((ext_vector_type(4)));
typedef float  f2v     __attribute__((ext_vector_type(2)));
typedef unsigned short ushort4_ __attribute__((ext_vector_type(4)));

__device__ __forceinline__ short f2bf(float f) {   // fp32 -> bf16 RNE (prep)
    uint32_t u = __float_as_uint(f);
    u += 0x7FFFu + ((u >> 16) & 1u);
    return (short)(u >> 16);
}
// packed RNE: lo=bf16(a), hi=bf16(b). Proven bit-exact (R5-R7).
__device__ __forceinline__ unsigned pk2bf(float a, float b) {
    unsigned ua = __float_as_uint(a), ub = __float_as_uint(b);
    ua += 0x7FFFu + ((ua >> 16) & 1u);
    ub += 0x7FFFu + ((ub >> 16) & 1u);
    return __builtin_amdgcn_perm(ub, ua, 0x07060302u);
}
__device__ __forceinline__ float bf2f(unsigned short u) {
    return __uint_as_float(((unsigned)u) << 16);
}
// pinned-issue 8B load: volatile asm cannot be sunk by the scheduler.
__device__ __forceinline__ f2v gload2(const float* p) {
    f2v r;
    asm volatile("global_load_dwordx2 %0, %1, off" : "=v"(r) : "v"(p) : "memory");
    return r;
}
// barrier with LDS-only drain (stores stay in flight across iterations)
#define SYNC_LGKM() do { \
    asm volatile("s_waitcnt lgkmcnt(0)" ::: "memory"); \
    __builtin_amdgcn_s_barrier(); \
    asm volatile("" ::: "memory"); } while (0)

// prep: W -> bf16 [os][c]; PA -> bf16 transposed+padded [s][w32][v32]; BN fold.
__global__ void stgcn_prep(const float* __restrict__ Wc, const float* __restrict__ PA,
                           const float* __restrict__ g,  const float* __restrict__ b,
                           const float* __restrict__ mn, const float* __restrict__ vr,
                           short* __restrict__ Wb, short* __restrict__ PAb,
                           float* __restrict__ scl, float* __restrict__ sft)
{
    const int i = blockIdx.x * 256 + threadIdx.x;
    if (i < OS_ * C_) Wb[i] = f2bf(Wc[i]);
    const int r = i - OS_ * C_;
    if (r >= 0 && r < S_ * 32 * 32) {
        const int s = r >> 10, rem = r & 1023, wp = rem >> 5, vp = rem & 31;
        const float val = (wp < V_ && vp < V_) ? PA[s * V_ * V_ + vp * V_ + wp] : 0.0f;
        PAb[r] = f2bf(val);
    }
    const int q = r - S_ * 32 * 32;
    if (q >= 0 && q < O_) {
        const float sc = g[q] * rsqrtf(vr[q] + 1e-5f);
        scl[q] = sc;
        sft[q] = b[q] - mn[q] * sc;
    }
}

__global__ __launch_bounds__(256, 4)
void stgcn_main(const float* __restrict__ x, const float* __restrict__ cb,
                const short* __restrict__ Wb, const short* __restrict__ PAb,
                const float* __restrict__ sclg, const float* __restrict__ sftg,
                float* __restrict__ out)
{
    __shared__ short Xb[2][64 * XPITCH];   // 18.4 KB (double-buffered)
    __shared__ uint2 sbuf[2][4 * 4 * 64];  // 16.4 KB: rotating per-s handoff
    __shared__ float sclS[O_], sftS[O_];   // total 35,328 B -> 4 blocks/CU

    const int tid  = threadIdx.x;
    const int wv   = tid >> 6;
    const int lane = tid & 63;
    const int quad = lane >> 4;
    const int l15  = lane & 15;

    const int n  = blockIdx.x / NT_BLK;
    const int t0 = (blockIdx.x % NT_BLK) * TB;
    const size_t xbase = (size_t)n * CTVM;

    // zero v-pad rows (pos 25..31, 57..63) of BOTH X buffers, once
    for (int i = tid; i < 2 * 14 * XPITCH; i += 256) {
        const int bf = i / (14 * XPITCH);
        const int r  = i - bf * (14 * XPITCH);
        const int pr = r / XPITCH, cc = r - pr * XPITCH;
        const int pos = (pr < 7) ? (25 + pr) : (50 + pr);
        Xb[bf][pos * XPITCH + cc] = 0;
    }
    if (tid < O_) { sclS[tid] = sclg[tid]; sftS[tid] = sftg[tid]; }

    // ---- wave-constant fragments ----
    const int osb = wv * 16;              // wave's o-block
    short8 aW[3][2];                      // stage-1 B: B[k=c][n=os]
    #pragma unroll
    for (int s = 0; s < 3; ++s)
        #pragma unroll
        for (int ks = 0; ks < 2; ++ks)
            aW[s][ks] = *(const short8*)(Wb + (s * 64 + osb + l15) * C_ + ks * 32 + quad * 8);

    float cbw[3];                         // stage-1 bias per COLUMN (os = l15)
    #pragma unroll
    for (int s = 0; s < 3; ++s) cbw[s] = cb[s * 64 + osb + l15];

    short8 bPf[3][2];                     // stage-2 B: B[k=v][n=w], both w-halves
    #pragma unroll
    for (int s = 0; s < 3; ++s)
        #pragma unroll
        for (int wh = 0; wh < 2; ++wh)
            bPf[s][wh] = *(const short8*)(PAb + s * 1024 + (wh * 16 + l15) * 32 + quad * 8);

    // per-thread prefetch geometry (k=0..2 always valid; k=3 clamped to p=799)
    int cpk[4], vk[4];
    #pragma unroll
    for (int k = 0; k < 4; ++k) {
        int p = tid + k * 256; if (p > 799) p = 799;
        cpk[k] = p / 25; vk[k] = p - cpk[k] * 25;
    }

    // ---- prologue: stage t0 into Xb[0] (blocking, once per block) ----
    {
        const float* xt = x + xbase + (size_t)t0 * VM;
        #pragma unroll
        for (int k = 0; k < 4; ++k) {
            const int p = tid + k * 256;
            if (p < 800) {
                const int v = vk[k], cp = cpk[k];
                const float2 f0 = *(const float2*)(xt + (size_t)(2 * cp)     * TVM + v * 2);
                const float2 f1 = *(const float2*)(xt + (size_t)(2 * cp + 1) * TVM + v * 2);
                ((unsigned*)Xb[0])[v * 36 + cp]        = pk2bf(f0.x, f1.x);  // m=0
                ((unsigned*)Xb[0])[(32 + v) * 36 + cp] = pk2bf(f0.y, f1.y);  // m=1
            }
        }
    }

    int cur = 0;
    for (int tt = 0; tt < TB; ++tt) {
        SYNC_LGKM();   // B0 (only barrier): Xb[cur] staged; stores NOT drained

        // ---- pinned-issue prefetch for t+1 (waited at convert, below) ----
        f2v R0[4], R1[4];
        const bool pf = (tt + 1 < TB);
        if (pf) {
            const float* xt = x + xbase + (size_t)(t0 + tt + 1) * VM;
            #pragma unroll
            for (int k = 0; k < 4; ++k) {
                const float* g0 = xt + (size_t)(2 * cpk[k]) * TVM + vk[k] * 2;
                R0[k] = gload2(g0);
                R1[k] = gload2(g0 + TVM);
            }
        }

        // ---- stage-1 A frags + residual from Xb[cur] ----
        const short* Xc = Xb[cur];
        short8 bX[4][2];                  // A[m=pos][k=c]
        #pragma unroll
        for (int nt = 0; nt < 4; ++nt)
            #pragma unroll
            for (int ks = 0; ks < 2; ++ks)
                bX[nt][ks] = *(const short8*)(Xc + (nt * 16 + l15) * XPITCH + ks * 32 + quad * 8);

        ushort4_ res[2][2];               // [m][wh]: residual bf16, o = osb+4*quad+r
        #pragma unroll
        for (int m = 0; m < 2; ++m)
            #pragma unroll
            for (int wh = 0; wh < 2; ++wh)
                res[m][wh] = *(const ushort4_*)(Xc + (m * 32 + wh * 16 + l15) * XPITCH + osb + quad * 4);

        // ---- fused stage1->stage2 per subset s (rotating 8KB handoff bufs) ----
        float4_ z[2][2];
        #pragma unroll
        for (int m = 0; m < 2; ++m)
            #pragma unroll
            for (int wh = 0; wh < 2; ++wh) { z[m][wh][0]=0.f; z[m][wh][1]=0.f; z[m][wh][2]=0.f; z[m][wh][3]=0.f; }

        const int lanepart = (((lane >> 4) & 1) * 32) + l15;   // src-lane base
        const int ntq      = (lane >> 5);                      // quad>>1
        #pragma unroll
        for (int s = 0; s < 3; ++s) {
            uint2* sb = sbuf[s & 1] + wv * 256;
            // stage 1, subset s: D[pos][o] = X^T·W_s^T + cb_s -> 4 packed tiles
            #pragma unroll
            for (int nt = 0; nt < 4; ++nt) {
                float4_ acc = { cbw[s], cbw[s], cbw[s], cbw[s] };
                acc = __builtin_amdgcn_mfma_f32_16x16x32_bf16(bX[nt][0], aW[s][0], acc, 0, 0, 0);
                acc = __builtin_amdgcn_mfma_f32_16x16x32_bf16(bX[nt][1], aW[s][1], acc, 0, 0, 0);
                sb[nt * 64 + lane] = make_uint2(pk2bf(acc[0], acc[1]), pk2bf(acc[2], acc[3]));
            }
            // short same-wave fence: 4 writes landed (scr is wave-private)
            asm volatile("s_waitcnt lgkmcnt(0)" ::: "memory");
            __builtin_amdgcn_sched_barrier(0);
            // stage 2, subset s: z[m][wh] += Y_s[o][v]·PA_s[v][w]
            #pragma unroll
            for (int m = 0; m < 2; ++m) {
                union { short8 s8; uint2 u2[2]; } aY;
                const uint2* sr = sb + (2 * m + ntq) * 64;
                aY.u2[0] = sr[lanepart];
                aY.u2[1] = sr[lanepart + 16];
                #pragma unroll
                for (int wh = 0; wh < 2; ++wh)
                    z[m][wh] = __builtin_amdgcn_mfma_f32_16x16x32_bf16(aY.s8, bPf[s][wh], z[m][wh], 0, 0, 0);
            }
        }

        // ---- convert prefetched regs into Xb[cur^1] (BEFORE epilogue stores) ----
        if (pf) {
            // data-carrying fence: every use below consumes these fenced defs
            asm volatile("s_waitcnt vmcnt(0)"
                : "+v"(R0[0]), "+v"(R0[1]), "+v"(R0[2]), "+v"(R0[3]),
                  "+v"(R1[0]), "+v"(R1[1]), "+v"(R1[2]), "+v"(R1[3])
                :: "memory");
            __builtin_amdgcn_sched_barrier(0);
            short* Xn = Xb[cur ^ 1];
            #pragma unroll
            for (int k = 0; k < 4; ++k) {
                const int p = tid + k * 256;
                if (p < 800) {
                    const int v = vk[k], cp = cpk[k];
                    ((unsigned*)Xn)[v * 36 + cp]        = pk2bf(R0[k][0], R1[k][0]);  // m=0
                    ((unsigned*)Xn)[(32 + v) * 36 + cp] = pk2bf(R0[k][1], R1[k][1]);  // m=1
                }
            }
        }

        // ---- epilogue: BN + relu + residual + relu; dense float2 stores ----
        const int t = t0 + tt;
        #pragma unroll
        for (int wh = 0; wh < 2; ++wh) {
            const int w = wh * 16 + l15;
            if (w < V_) {
                #pragma unroll
                for (int r = 0; r < 4; ++r) {
                    const int o = osb + quad * 4 + r;
                    const float sc = sclS[o], sh = sftS[o];
                    float q0 = fmaf(z[0][wh][r], sc, sh);
                    q0 = fmaxf(q0, 0.0f);
                    q0 = fmaxf(q0 + bf2f((unsigned short)res[0][wh][r]), 0.0f);
                    float q1 = fmaf(z[1][wh][r], sc, sh);
                    q1 = fmaxf(q1, 0.0f);
                    q1 = fmaxf(q1 + bf2f((unsigned short)res[1][wh][r]), 0.0f);
                    *(float2*)(out + xbase + (size_t)o * TVM + (size_t)t * VM + w * 2) =
                        make_float2(q0, q1);
                }
            }
        }
        cur ^= 1;
    }
}

extern "C" void kernel_launch(void* const* d_in, const int* in_sizes, int n_in,
                              void* d_out, int out_size, void* d_ws, size_t ws_size,
                              hipStream_t stream)
{
    const float* x    = (const float*)d_in[0];  // (32,64,300,25,2)
    const float* PA   = (const float*)d_in[1];  // (3,25,25)
    const float* Wc   = (const float*)d_in[2];  // (192,64)
    const float* cb   = (const float*)d_in[3];  // (192,)
    const float* bn_g = (const float*)d_in[4];
    const float* bn_b = (const float*)d_in[5];
    const float* bn_m = (const float*)d_in[6];
    const float* bn_v = (const float*)d_in[7];
    float* out = (float*)d_out;

    char* ws = (char*)d_ws;
    short* Wb  = (short*)ws;                    // 12288 bf16
    short* PAb = (short*)(ws + 24576);          //  3072 bf16
    float* scl = (float*)(ws + 30720);          //    64 f32
    float* sft = (float*)(ws + 30976);          //    64 f32

    stgcn_prep<<<61, 256, 0, stream>>>(Wc, PA, bn_g, bn_b, bn_m, bn_v, Wb, PAb, scl, sft);
    stgcn_main<<<N_ * NT_BLK, 256, 0, stream>>>(x, cb, Wb, PAb, scl, sft, out);
}

// Round 9
// 330.430 us; speedup vs baseline: 1.2372x; 1.2372x over previous
//
#include <hip/hip_runtime.h>
#include <cstddef>
#include <cstdint>

// ST-GCN block. Round-9: R8's small-LDS structure, but occupancy from HARDWARE
// limits, not launch_bounds.
//  R8 post-mortem: __launch_bounds__(256,4) set a 64-VGPR allocator target; the
//  ~90-VGPR persistent state spilled to scratch (VGPR=64, FETCH 72->375MB,
//  241us). Third allocator disaster from requesting occupancy via launch_bounds.
//  The fix (this round): keep (256,3) -> compiler allocates ~84 VGPRs freely;
//  HW VGPR occupancy granule (m69: steps at 64/128/256) grants 4 waves/SIMD at
//  84 VGPRs, and LDS 35,328B < 40,960B permits 4 blocks/CU. So 4 blocks/CU
//  arrives with ZERO allocator pressure. This cleanly tests the R7 TLP theory.
//  Kept (verified): single barrier/iter (lgkm-only drain), o-block wave mapping,
//  per-s rotating 8KB handoff (short fence hops), pinned-issue prefetch +
//  data-carrying vmcnt fence, dense float2 epilogue.
// Sync proof: [B0_t, B0_{t+1}): Xb[cur] read-only, Xb[cur^1] written only by
//   convert (ordered by B0's lgkmcnt(0)+barrier). sbuf[*] wave-private
//   (same-wave in-order DS + per-s lgkmcnt(0) fences; MFMA data-deps force
//   s-read completion before next s overwrites).
#define N_  32
#define C_  64
#define T_  300
#define V_  25
#define M_  2
#define S_  3
#define O_  64
#define OS_ 192
#define TB  6             // t-values per block
#define NT_BLK (T_/TB)    // 50
#define CTVM (C_*T_*V_*M_)   // 960000
#define TVM  (T_*V_*M_)      // 15000
#define VM   (V_*M_)         // 50
#define XPITCH 72         // shorts; 144B rows

typedef short  short8  __attribute__((ext_vector_type(8)));
typedef float  float4_ __attribute__((ext_vector_type(4)));
typedef float  f2v     __attribute__((ext_vector_type(2)));
typedef unsigned short ushort4_ __attribute__((ext_vector_type(4)));

__device__ __forceinline__ short f2bf(float f) {   // fp32 -> bf16 RNE (prep)
    uint32_t u = __float_as_uint(f);
    u += 0x7FFFu + ((u >> 16) & 1u);
    return (short)(u >> 16);
}
// packed RNE: lo=bf16(a), hi=bf16(b). Proven bit-exact (R5-R8).
__device__ __forceinline__ unsigned pk2bf(float a, float b) {
    unsigned ua = __float_as_uint(a), ub = __float_as_uint(b);
    ua += 0x7FFFu + ((ua >> 16) & 1u);
    ub += 0x7FFFu + ((ub >> 16) & 1u);
    return __builtin_amdgcn_perm(ub, ua, 0x07060302u);
}
__device__ __forceinline__ float bf2f(unsigned short u) {
    return __uint_as_float(((unsigned)u) << 16);
}
// pinned-issue 8B load: volatile asm cannot be sunk by the scheduler.
__device__ __forceinline__ f2v gload2(const float* p) {
    f2v r;
    asm volatile("global_load_dwordx2 %0, %1, off" : "=v"(r) : "v"(p) : "memory");
    return r;
}
// barrier with LDS-only drain (stores stay in flight across iterations)
#define SYNC_LGKM() do { \
    asm volatile("s_waitcnt lgkmcnt(0)" ::: "memory"); \
    __builtin_amdgcn_s_barrier(); \
    asm volatile("" ::: "memory"); } while (0)

// prep: W -> bf16 [os][c]; PA -> bf16 transposed+padded [s][w32][v32]; BN fold.
__global__ void stgcn_prep(const float* __restrict__ Wc, const float* __restrict__ PA,
                           const float* __restrict__ g,  const float* __restrict__ b,
                           const float* __restrict__ mn, const float* __restrict__ vr,
                           short* __restrict__ Wb, short* __restrict__ PAb,
                           float* __restrict__ scl, float* __restrict__ sft)
{
    const int i = blockIdx.x * 256 + threadIdx.x;
    if (i < OS_ * C_) Wb[i] = f2bf(Wc[i]);
    const int r = i - OS_ * C_;
    if (r >= 0 && r < S_ * 32 * 32) {
        const int s = r >> 10, rem = r & 1023, wp = rem >> 5, vp = rem & 31;
        const float val = (wp < V_ && vp < V_) ? PA[s * V_ * V_ + vp * V_ + wp] : 0.0f;
        PAb[r] = f2bf(val);
    }
    const int q = r - S_ * 32 * 32;
    if (q >= 0 && q < O_) {
        const float sc = g[q] * rsqrtf(vr[q] + 1e-5f);
        scl[q] = sc;
        sft[q] = b[q] - mn[q] * sc;
    }
}

__global__ __launch_bounds__(256, 3)
void stgcn_main(const float* __restrict__ x, const float* __restrict__ cb,
                const short* __restrict__ Wb, const short* __restrict__ PAb,
                const float* __restrict__ sclg, const float* __restrict__ sftg,
                float* __restrict__ out)
{
    __shared__ short Xb[2][64 * XPITCH];   // 18.4 KB (double-buffered)
    __shared__ uint2 sbuf[2][4 * 4 * 64];  // 16.4 KB: rotating per-s handoff
    __shared__ float sclS[O_], sftS[O_];   // total 35,328 B -> 4 blocks/CU (LDS)

    const int tid  = threadIdx.x;
    const int wv   = tid >> 6;
    const int lane = tid & 63;
    const int quad = lane >> 4;
    const int l15  = lane & 15;

    const int n  = blockIdx.x / NT_BLK;
    const int t0 = (blockIdx.x % NT_BLK) * TB;
    const size_t xbase = (size_t)n * CTVM;

    // zero v-pad rows (pos 25..31, 57..63) of BOTH X buffers, once
    for (int i = tid; i < 2 * 14 * XPITCH; i += 256) {
        const int bf = i / (14 * XPITCH);
        const int r  = i - bf * (14 * XPITCH);
        const int pr = r / XPITCH, cc = r - pr * XPITCH;
        const int pos = (pr < 7) ? (25 + pr) : (50 + pr);
        Xb[bf][pos * XPITCH + cc] = 0;
    }
    if (tid < O_) { sclS[tid] = sclg[tid]; sftS[tid] = sftg[tid]; }

    // ---- wave-constant fragments ----
    const int osb = wv * 16;              // wave's o-block
    short8 aW[3][2];                      // stage-1 B: B[k=c][n=os]
    #pragma unroll
    for (int s = 0; s < 3; ++s)
        #pragma unroll
        for (int ks = 0; ks < 2; ++ks)
            aW[s][ks] = *(const short8*)(Wb + (s * 64 + osb + l15) * C_ + ks * 32 + quad * 8);

    float cbw[3];                         // stage-1 bias per COLUMN (os = l15)
    #pragma unroll
    for (int s = 0; s < 3; ++s) cbw[s] = cb[s * 64 + osb + l15];

    short8 bPf[3][2];                     // stage-2 B: B[k=v][n=w], both w-halves
    #pragma unroll
    for (int s = 0; s < 3; ++s)
        #pragma unroll
        for (int wh = 0; wh < 2; ++wh)
            bPf[s][wh] = *(const short8*)(PAb + s * 1024 + (wh * 16 + l15) * 32 + quad * 8);

    // per-thread prefetch geometry (k=0..2 always valid; k=3 clamped to p=799)
    int cpk[4], vk[4];
    #pragma unroll
    for (int k = 0; k < 4; ++k) {
        int p = tid + k * 256; if (p > 799) p = 799;
        cpk[k] = p / 25; vk[k] = p - cpk[k] * 25;
    }

    // ---- prologue: stage t0 into Xb[0] (blocking, once per block) ----
    {
        const float* xt = x + xbase + (size_t)t0 * VM;
        #pragma unroll
        for (int k = 0; k < 4; ++k) {
            const int p = tid + k * 256;
            if (p < 800) {
                const int v = vk[k], cp = cpk[k];
                const float2 f0 = *(const float2*)(xt + (size_t)(2 * cp)     * TVM + v * 2);
                const float2 f1 = *(const float2*)(xt + (size_t)(2 * cp + 1) * TVM + v * 2);
                ((unsigned*)Xb[0])[v * 36 + cp]        = pk2bf(f0.x, f1.x);  // m=0
                ((unsigned*)Xb[0])[(32 + v) * 36 + cp] = pk2bf(f0.y, f1.y);  // m=1
            }
        }
    }

    int cur = 0;
    for (int tt = 0; tt < TB; ++tt) {
        SYNC_LGKM();   // B0 (only barrier): Xb[cur] staged; stores NOT drained

        // ---- pinned-issue prefetch for t+1 (waited at convert, below) ----
        f2v R0[4], R1[4];
        const bool pf = (tt + 1 < TB);
        if (pf) {
            const float* xt = x + xbase + (size_t)(t0 + tt + 1) * VM;
            #pragma unroll
            for (int k = 0; k < 4; ++k) {
                const float* g0 = xt + (size_t)(2 * cpk[k]) * TVM + vk[k] * 2;
                R0[k] = gload2(g0);
                R1[k] = gload2(g0 + TVM);
            }
        }

        // ---- stage-1 A frags + residual from Xb[cur] ----
        const short* Xc = Xb[cur];
        short8 bX[4][2];                  // A[m=pos][k=c]
        #pragma unroll
        for (int nt = 0; nt < 4; ++nt)
            #pragma unroll
            for (int ks = 0; ks < 2; ++ks)
                bX[nt][ks] = *(const short8*)(Xc + (nt * 16 + l15) * XPITCH + ks * 32 + quad * 8);

        ushort4_ res[2][2];               // [m][wh]: residual bf16, o = osb+4*quad+r
        #pragma unroll
        for (int m = 0; m < 2; ++m)
            #pragma unroll
            for (int wh = 0; wh < 2; ++wh)
                res[m][wh] = *(const ushort4_*)(Xc + (m * 32 + wh * 16 + l15) * XPITCH + osb + quad * 4);

        // ---- fused stage1->stage2 per subset s (rotating 8KB handoff bufs) ----
        float4_ z[2][2];
        #pragma unroll
        for (int m = 0; m < 2; ++m)
            #pragma unroll
            for (int wh = 0; wh < 2; ++wh) { z[m][wh][0]=0.f; z[m][wh][1]=0.f; z[m][wh][2]=0.f; z[m][wh][3]=0.f; }

        const int lanepart = (((lane >> 4) & 1) * 32) + l15;   // src-lane base
        const int ntq      = (lane >> 5);                      // quad>>1
        #pragma unroll
        for (int s = 0; s < 3; ++s) {
            uint2* sb = sbuf[s & 1] + wv * 256;
            // stage 1, subset s: D[pos][o] = X^T·W_s^T + cb_s -> 4 packed tiles
            #pragma unroll
            for (int nt = 0; nt < 4; ++nt) {
                float4_ acc = { cbw[s], cbw[s], cbw[s], cbw[s] };
                acc = __builtin_amdgcn_mfma_f32_16x16x32_bf16(bX[nt][0], aW[s][0], acc, 0, 0, 0);
                acc = __builtin_amdgcn_mfma_f32_16x16x32_bf16(bX[nt][1], aW[s][1], acc, 0, 0, 0);
                sb[nt * 64 + lane] = make_uint2(pk2bf(acc[0], acc[1]), pk2bf(acc[2], acc[3]));
            }
            // short same-wave fence: 4 writes landed (sbuf slice is wave-private)
            asm volatile("s_waitcnt lgkmcnt(0)" ::: "memory");
            __builtin_amdgcn_sched_barrier(0);
            // stage 2, subset s: z[m][wh] += Y_s[o][v]·PA_s[v][w]
            #pragma unroll
            for (int m = 0; m < 2; ++m) {
                union { short8 s8; uint2 u2[2]; } aY;
                const uint2* sr = sb + (2 * m + ntq) * 64;
                aY.u2[0] = sr[lanepart];
                aY.u2[1] = sr[lanepart + 16];
                #pragma unroll
                for (int wh = 0; wh < 2; ++wh)
                    z[m][wh] = __builtin_amdgcn_mfma_f32_16x16x32_bf16(aY.s8, bPf[s][wh], z[m][wh], 0, 0, 0);
            }
        }

        // ---- convert prefetched regs into Xb[cur^1] (BEFORE epilogue stores) ----
        if (pf) {
            // data-carrying fence: every use below consumes these fenced defs
            asm volatile("s_waitcnt vmcnt(0)"
                : "+v"(R0[0]), "+v"(R0[1]), "+v"(R0[2]), "+v"(R0[3]),
                  "+v"(R1[0]), "+v"(R1[1]), "+v"(R1[2]), "+v"(R1[3])
                :: "memory");
            __builtin_amdgcn_sched_barrier(0);
            short* Xn = Xb[cur ^ 1];
            #pragma unroll
            for (int k = 0; k < 4; ++k) {
                const int p = tid + k * 256;
                if (p < 800) {
                    const int v = vk[k], cp = cpk[k];
                    ((unsigned*)Xn)[v * 36 + cp]        = pk2bf(R0[k][0], R1[k][0]);  // m=0
                    ((unsigned*)Xn)[(32 + v) * 36 + cp] = pk2bf(R0[k][1], R1[k][1]);  // m=1
                }
            }
        }

        // ---- epilogue: BN + relu + residual + relu; dense float2 stores ----
        const int t = t0 + tt;
        #pragma unroll
        for (int wh = 0; wh < 2; ++wh) {
            const int w = wh * 16 + l15;
            if (w < V_) {
                #pragma unroll
                for (int r = 0; r < 4; ++r) {
                    const int o = osb + quad * 4 + r;
                    const float sc = sclS[o], sh = sftS[o];
                    float q0 = fmaf(z[0][wh][r], sc, sh);
                    q0 = fmaxf(q0, 0.0f);
                    q0 = fmaxf(q0 + bf2f((unsigned short)res[0][wh][r]), 0.0f);
                    float q1 = fmaf(z[1][wh][r], sc, sh);
                    q1 = fmaxf(q1, 0.0f);
                    q1 = fmaxf(q1 + bf2f((unsigned short)res[1][wh][r]), 0.0f);
                    *(float2*)(out + xbase + (size_t)o * TVM + (size_t)t * VM + w * 2) =
                        make_float2(q0, q1);
                }
            }
        }
        cur ^= 1;
    }
}

extern "C" void kernel_launch(void* const* d_in, const int* in_sizes, int n_in,
                              void* d_out, int out_size, void* d_ws, size_t ws_size,
                              hipStream_t stream)
{
    const float* x    = (const float*)d_in[0];  // (32,64,300,25,2)
    const float* PA   = (const float*)d_in[1];  // (3,25,25)
    const float* Wc   = (const float*)d_in[2];  // (192,64)
    const float* cb   = (const float*)d_in[3];  // (192,)
    const float* bn_g = (const float*)d_in[4];
    const float* bn_b = (const float*)d_in[5];
    const float* bn_m = (const float*)d_in[6];
    const float* bn_v = (const float*)d_in[7];
    float* out = (float*)d_out;

    char* ws = (char*)d_ws;
    short* Wb  = (short*)ws;                    // 12288 bf16
    short* PAb = (short*)(ws + 24576);          //  3072 bf16
    float* scl = (float*)(ws + 30720);          //    64 f32
    float* sft = (float*)(ws + 30976);          //    64 f32

    stgcn_prep<<<61, 256, 0, stream>>>(Wc, PA, bn_g, bn_b, bn_m, bn_v, Wb, PAb, scl, sft);
    stgcn_main<<<N_ * NT_BLK, 256, 0, stream>>>(x, cb, Wb, PAb, scl, sft, out);
}